// Round 24
// baseline (247.308 us; speedup 1.0000x reference)
//
#include <hip/hip_runtime.h>
#include <hip/hip_fp16.h>

#define NN      262144    // N = B*WIN_IN*NODES
#define EDGES   2097152
#define FEATD   16
#define HIDD    64
#define LSTMH   32
#define BATCH   64
#define WIN     32
#define WOUT    8
#define NCLS    10
#define ROWD    2048      // NODES*FEAT = B*WIN (both 2048)
#define KCHUNKS 16
#define KSPAN   (ROWD / KCHUNKS)   // 128

#define NB2     512       // dest buckets: c >> 9 (512 nodes each)
#define NW      512       // nodes per bucket
#define CAPB    4608      // per-bucket capacity: Poisson(4096)+8 sigma
#define NBLK    256       // edge chunks
#define CHUNK   (EDGES / NBLK)   // 8192 edges per chunk

typedef __fp16 half4v __attribute__((ext_vector_type(4)));
typedef float  float4v __attribute__((ext_vector_type(4)));

// ---- phase 1: per-(block,bucket) histogram ----
__global__ void k_hist(const int* __restrict__ ei, int* __restrict__ hist2d) {
    __shared__ int h[NB2];
    int blk = blockIdx.x, tid = threadIdx.x;
    for (int l = tid; l < NB2; l += 256) h[l] = 0;
    __syncthreads();
    int e0 = blk * CHUNK;
    for (int i = tid; i < CHUNK; i += 256)
        atomicAdd(&h[ei[EDGES + e0 + i] >> 9], 1);
    __syncthreads();
    for (int l = tid; l < NB2; l += 256) hist2d[l * NBLK + blk] = h[l];
}

// ---- phase 2: per-bucket exclusive scan over block counts; totals -> bcnt ----
__global__ void k_scan2(int* __restrict__ hist2d, int* __restrict__ bcnt) {
    __shared__ int s[NBLK];
    int b = blockIdx.x, tid = threadIdx.x;
    int v = hist2d[b * NBLK + tid];
    s[tid] = v;
    __syncthreads();
    for (int off = 1; off < NBLK; off <<= 1) {
        int t = (tid >= off) ? s[tid - off] : 0;
        __syncthreads();
        s[tid] += t;
        __syncthreads();
    }
    hist2d[b * NBLK + tid] = s[tid] - v;   // exclusive base for (bucket, block)
    if (tid == NBLK - 1) bcnt[b] = s[tid];
}

// ---- phase 3: place edges into block-private contiguous runs (full lines) ----
__global__ void k_place(const int* __restrict__ ei, const int* __restrict__ hist2d,
                        int* __restrict__ bdata) {
    __shared__ int curp[NB2];
    int blk = blockIdx.x, tid = threadIdx.x;
    for (int l = tid; l < NB2; l += 256) curp[l] = hist2d[l * NBLK + blk];
    __syncthreads();
    int e0 = blk * CHUNK;
    for (int i = tid; i < CHUNK; i += 256) {
        int r = ei[e0 + i];
        int c = ei[EDGES + e0 + i];
        int b = c >> 9;
        int p = atomicAdd(&curp[b], 1);
        if (p < CAPB) bdata[(size_t)b * CAPB + p] = (r << 9) | (c & 511);
    }
}

// ---- per-bucket LDS counting sort (512 threads) + fused dinv + x pre-scale ----
__global__ void __launch_bounds__(512)
k_csrsort(const int* __restrict__ bcnt, const int* __restrict__ bdata,
          int* __restrict__ rows, int* __restrict__ offp, float* __restrict__ dinv,
          const float* __restrict__ x, __half2* __restrict__ xsH) {
    __shared__ int sidx[CAPB];          // 18.4 KB
    __shared__ int sorted[CAPB];        // 18.4 KB
    __shared__ int hist[NW], curp[NW], ssc[NW];
    __shared__ float sdinv[NW];
    int b = blockIdx.x, tid = threadIdx.x;
    int total = bcnt[b]; if (total > CAPB) total = CAPB;
    hist[tid] = 0;
    __syncthreads();
    const int* base = bdata + (size_t)b * CAPB;
    for (int i = tid; i < total; i += 512) {
        int w = base[i];
        sidx[i] = w;
        atomicAdd(&hist[w & 511], 1);
    }
    __syncthreads();
    int v = hist[tid];
    ssc[tid] = v;
    __syncthreads();
    for (int st = 1; st < NW; st <<= 1) {
        int t = (tid >= st) ? ssc[tid - st] : 0;
        __syncthreads();
        ssc[tid] += t;
        __syncthreads();
    }
    float dval = rsqrtf((float)v + 1.0f);
    curp[tid] = ssc[tid] - v;                       // exclusive start
    offp[b * NW + tid] = ssc[tid];                  // inclusive end
    dinv[b * NW + tid] = dval;                      // degree byproduct
    sdinv[tid] = dval;
    __syncthreads();
    for (int i = tid; i < total; i += 512) {
        int w = sidx[i];
        int pos = atomicAdd(&curp[w & 511], 1);
        sorted[pos] = w >> 9;
    }
    // fused pre-scale for this bucket's 512 nodes
    for (int i = tid; i < NW * 8; i += 512) {
        int nl = i >> 3;
        float d = sdinv[nl];
        float2 xv = ((const float2*)x)[(size_t)(b * NW) * 8 + i];
        xsH[(size_t)(b * NW) * 8 + i] = __floats2half2_rn(xv.x * d, xv.y * d);
    }
    __syncthreads();
    for (int i = tid; i < total; i += 512) rows[(size_t)b * CAPB + i] = sorted[i];
}

// ---- Wih f32 -> f16 ----
__global__ void k_wihcvt(const float* __restrict__ Wih, __half2* __restrict__ WihH) {
    int i = blockIdx.x * blockDim.x + threadIdx.x;   // 65536 float4 lanes
    if (i >= 128 * ROWD / 4) return;
    float4 v = ((const float4*)Wih)[i];
    WihH[i * 2 + 0] = __floats2half2_rn(v.x, v.y);
    WihH[i * 2 + 1] = __floats2half2_rn(v.z, v.w);
}

// ---- fused layer-1 aggregation + MLP ----
// Block = 256 nodes. Phase 1: 8 sweeps of 32 nodes, 8 lanes/node gather in1
// into LDS (f32). Phase 2: one node per thread, MLP, t2s -> fp16 into t2sH.
__global__ void __launch_bounds__(256)
k_agg1mlp(const int* __restrict__ rows, const int* __restrict__ off,
          const float* __restrict__ dinv, const __half2* __restrict__ xsH,
          const float* __restrict__ W1, const float* __restrict__ b1,
          const float* __restrict__ W2, __half2* __restrict__ t2sH) {
    __shared__ float sin[256][FEATD + 1];   // 17.4 KB
    __shared__ float sW1[FEATD * HIDD];
    __shared__ float sW2[HIDD * FEATD];
    __shared__ float sb1[HIDD];
    int tid = threadIdx.x;
    for (int l = tid; l < FEATD * HIDD; l += 256) {
        sW1[l] = W1[l];
        sW2[l] = W2[l];
    }
    if (tid < HIDD) sb1[tid] = b1[tid];
    int nbase = blockIdx.x * 256;
    int f2 = tid & 7;
    int nl = tid >> 3;           // 0..31
#pragma unroll
    for (int s = 0; s < 8; s++) {
        int n = nbase + s * 32 + nl;
        int begin = (n & 511) ? off[n - 1] : 0;
        int end = off[n];
        const size_t base = (size_t)(n >> 9) * CAPB;
        float2 sv = __half22float2(xsH[(size_t)n * 8 + f2]);
        float ax = sv.x, ay = sv.y;
        for (size_t e = base + begin; e < base + end; ++e) {
            int r = rows[e];
            float2 v = __half22float2(xsH[(size_t)r * 8 + f2]);
            ax += v.x; ay += v.y;
        }
        float d = dinv[n];
        sin[s * 32 + nl][f2 * 2 + 0] = ax * d;
        sin[s * 32 + nl][f2 * 2 + 1] = ay * d;
    }
    __syncthreads();
    int n = nbase + tid;
    float in[FEATD];
#pragma unroll
    for (int f = 0; f < FEATD; f++) in[f] = sin[tid][f];
    float out[FEATD];
#pragma unroll
    for (int c = 0; c < FEATD; c++) out[c] = 0.f;
#pragma unroll 8
    for (int j = 0; j < HIDD; j++) {
        float h = sb1[j];
#pragma unroll
        for (int f = 0; f < FEATD; f++) h += in[f] * sW1[f * HIDD + j];
        h = fmaxf(h, 0.f);
#pragma unroll
        for (int c = 0; c < FEATD; c++) out[c] += h * sW2[j * FEATD + c];
    }
    float dn = dinv[n];
    union { float4 f4; __half2 h2[4]; } o0, o1;
#pragma unroll
    for (int q = 0; q < 4; q++) {
        o0.h2[q] = __floats2half2_rn(out[q * 2] * dn, out[q * 2 + 1] * dn);
        o1.h2[q] = __floats2half2_rn(out[8 + q * 2] * dn, out[8 + q * 2 + 1] * dn);
    }
    ((float4*)(t2sH + (size_t)n * 8))[0] = o0.f4;
    ((float4*)(t2sH + (size_t)n * 8))[1] = o1.f4;
}

// ---- zero-atomic CSR gather-reduce, layer 2 (fused +b2, relu) ----
__global__ void __launch_bounds__(256)
k_aggcsr2(const int* __restrict__ rows, const int* __restrict__ off,
          const float* __restrict__ dinv, const __half2* __restrict__ srcH,
          const float* __restrict__ b2, __half2* __restrict__ outH) {
    int i = blockIdx.x * blockDim.x + threadIdx.x;
    if (i >= NN * 8) return;
    int n = i >> 3, f2 = i & 7;
    int begin = (n & 511) ? off[n - 1] : 0;
    int end = off[n];
    const size_t base = (size_t)(n >> 9) * CAPB;
    float2 selfv = __half22float2(srcH[(size_t)n * 8 + f2]);
    float ax = selfv.x, ay = selfv.y;
    for (size_t e = base + begin; e < base + end; ++e) {
        int r = rows[e];
        float2 v = __half22float2(srcH[(size_t)r * 8 + f2]);
        ax += v.x; ay += v.y;
    }
    float d = dinv[n];
    ax = fmaxf(ax * d + b2[f2 * 2 + 0], 0.f);
    ay = fmaxf(ay * d + b2[f2 * 2 + 1], 0.f);
    outH[i] = __floats2half2_rn(ax, ay);
}

// ---- LSTM input GEMM via MFMA 16x16x16 f16 ----
__global__ void __launch_bounds__(256)
k_gemmA(const __half* __restrict__ h2, const __half* __restrict__ WihH,
        float* __restrict__ gxp) {
    __shared__ __half Bs[128][KSPAN + 8];   // 34.8 KB
    int tid = threadIdx.x;
    int row0 = blockIdx.x * 32;
    int k0 = blockIdx.y * KSPAN;
    for (int idx = tid; idx < 128 * (KSPAN / 8); idx += 256) {
        int j = idx >> 4, c8 = (idx & 15) * 8;
        *(float4*)&Bs[j][c8] = *(const float4*)&WihH[(size_t)j * ROWD + k0 + c8];
    }
    __syncthreads();
    int w = tid >> 6;
    int l = tid & 63;
    int rt = w & 1;            // row tile (16 rows)
    int ch = w >> 1;           // col half (64 cols)
    int m = l & 15;
    int kg = l >> 4;
    float4v acc0 = {0.f, 0.f, 0.f, 0.f};
    float4v acc1 = {0.f, 0.f, 0.f, 0.f};
    float4v acc2 = {0.f, 0.f, 0.f, 0.f};
    float4v acc3 = {0.f, 0.f, 0.f, 0.f};
    const __half* aptr = h2 + (size_t)(row0 + rt * 16 + m) * ROWD + k0 + kg * 4;
#pragma unroll
    for (int kk = 0; kk < KSPAN; kk += 16) {
        half4v a = *(const half4v*)(aptr + kk);
        half4v b0 = *(const half4v*)&Bs[ch * 64 + 0 * 16 + m][kk + kg * 4];
        half4v b1 = *(const half4v*)&Bs[ch * 64 + 1 * 16 + m][kk + kg * 4];
        half4v b2 = *(const half4v*)&Bs[ch * 64 + 2 * 16 + m][kk + kg * 4];
        half4v b3 = *(const half4v*)&Bs[ch * 64 + 3 * 16 + m][kk + kg * 4];
        acc0 = __builtin_amdgcn_mfma_f32_16x16x16f16(a, b0, acc0, 0, 0, 0);
        acc1 = __builtin_amdgcn_mfma_f32_16x16x16f16(a, b1, acc1, 0, 0, 0);
        acc2 = __builtin_amdgcn_mfma_f32_16x16x16f16(a, b2, acc2, 0, 0, 0);
        acc3 = __builtin_amdgcn_mfma_f32_16x16x16f16(a, b3, acc3, 0, 0, 0);
    }
    float* ob = gxp + (size_t)blockIdx.y * (ROWD * 128) + (size_t)(row0 + rt * 16) * 128 + ch * 64;
#pragma unroll
    for (int i = 0; i < 4; i++) {
        size_t ro = (size_t)(kg * 4 + i) * 128;
        ob[ro + 0 * 16 + m] = acc0[i];
        ob[ro + 1 * 16 + m] = acc1[i];
        ob[ro + 2 * 16 + m] = acc2[i];
        ob[ro + 3 * 16 + m] = acc3[i];
    }
}

// ---- LSTM recurrence with fused gxp prereduce ----
__global__ void k_lstm(const float* __restrict__ gxp, const float* __restrict__ Whh,
                       const float* __restrict__ bih, const float* __restrict__ bhh,
                       float* __restrict__ hseq) {
    __shared__ float sWhhT[LSTMH][4 * LSTMH];   // [k][j] = Whh[j][k]
    __shared__ float sgxL[WIN * 4 * LSTMH];      // 16 KB
    __shared__ float sh[LSTMH], sc[LSTMH], sg[4 * LSTMH];
    int b = blockIdx.x, j = threadIdx.x;
    for (int l = j; l < 4 * LSTMH * LSTMH; l += 4 * LSTMH) {
        int r = l >> 5, k = l & 31;
        sWhhT[k][r] = Whh[l];
    }
    for (int l = j; l < WIN * 128; l += 128) {
        float s = 0.f;
#pragma unroll
        for (int p = 0; p < KCHUNKS; p++)
            s += gxp[(size_t)p * ROWD * 128 + (size_t)b * WIN * 128 + l];
        sgxL[l] = s;
    }
    float bias = bih[j] + bhh[j];
    if (j < LSTMH) { sh[j] = 0.f; sc[j] = 0.f; }
    __syncthreads();
    for (int t = 0; t < WIN; t++) {
        float g = bias + sgxL[t * 128 + j];
#pragma unroll
        for (int k = 0; k < LSTMH; k++) g += sWhhT[k][j] * sh[k];
        sg[j] = g;
        __syncthreads();
        if (j < LSTMH) {
            float ig = sg[j], fg = sg[32 + j], gg = sg[64 + j], og = sg[96 + j];
            float c = sc[j];
            float si = 1.f / (1.f + __expf(-ig));
            float sf = 1.f / (1.f + __expf(-fg));
            float so = 1.f / (1.f + __expf(-og));
            c = sf * c + si * tanhf(gg);
            float h = so * tanhf(c);
            sc[j] = c; sh[j] = h;
            if (t >= WIN - WOUT)
                hseq[(size_t)(b * WOUT + (t - (WIN - WOUT))) * LSTMH + j] = h;
        }
        __syncthreads();
    }
}

// ---- FC head: (512 rows) 32 -> 16 relu -> 10 ----
__global__ void k_fc(const float* __restrict__ hseq, const float* __restrict__ Wfc1,
                     const float* __restrict__ bfc1, const float* __restrict__ Wfc2,
                     const float* __restrict__ bfc2, float* __restrict__ out) {
    __shared__ float sW1[16 * 32], sb1[16], sW2[10 * 16], sb2[10];
    int tid = threadIdx.x;
    for (int l = tid; l < 16 * 32; l += blockDim.x) sW1[l] = Wfc1[l];
    if (tid < 16) sb1[tid] = bfc1[tid];
    for (int l = tid; l < 160; l += blockDim.x) sW2[l] = Wfc2[l];
    if (tid < 10) sb2[tid] = bfc2[tid];
    __syncthreads();
    int r = blockIdx.x * blockDim.x + tid;
    if (r >= BATCH * WOUT) return;
    float h[32];
#pragma unroll
    for (int k = 0; k < 32; k++) h[k] = hseq[(size_t)r * 32 + k];
    float hid[16];
#pragma unroll
    for (int j = 0; j < 16; j++) {
        float v = sb1[j];
#pragma unroll
        for (int k = 0; k < 32; k++) v += sW1[j * 32 + k] * h[k];
        hid[j] = fmaxf(v, 0.f);
    }
#pragma unroll
    for (int c = 0; c < NCLS; c++) {
        float v = sb2[c];
#pragma unroll
        for (int j = 0; j < 16; j++) v += sW2[c * 16 + j] * hid[j];
        out[(size_t)r * NCLS + c] = v;
    }
}

extern "C" void kernel_launch(void* const* d_in, const int* in_sizes, int n_in,
                              void* d_out, int out_size, void* d_ws, size_t ws_size,
                              hipStream_t stream) {
    const float* x    = (const float*)d_in[0];
    const int*   ei   = (const int*)d_in[1];
    const float* W1   = (const float*)d_in[2];
    const float* b1   = (const float*)d_in[3];
    const float* W2   = (const float*)d_in[4];
    const float* b2   = (const float*)d_in[5];
    const float* Wih  = (const float*)d_in[6];
    const float* Whh  = (const float*)d_in[7];
    const float* bih  = (const float*)d_in[8];
    const float* bhh  = (const float*)d_in[9];
    const float* Wfc1 = (const float*)d_in[10];
    const float* bfc1 = (const float*)d_in[11];
    const float* Wfc2 = (const float*)d_in[12];
    const float* bfc2 = (const float*)d_in[13];
    float* out = (float*)d_out;

    float*   ws     = (float*)d_ws;
    float*   dinv   = ws;                                    // NN f32 (1 MB)
    int*     hist2d = (int*)(dinv + NN);                     // NB2*NBLK ints (0.5 MB)
    int*     bcnt   = hist2d + NB2 * NBLK;                   // NB2 ints
    int*     off    = bcnt + NB2;                            // NN ints (1 MB)
    int*     rows   = off + NN;                              // NB2*CAPB ints (9.4 MB)
    __half2* aggH   = (__half2*)(rows + (size_t)NB2 * CAPB); // NN*8 half2 (8 MB): t2s
    __half2* xsH    = aggH + (size_t)NN * 8;                 // NN*8 half2 (8 MB): xs -> h2
    int*     bdata  = (int*)(xsH + (size_t)NN * 8);          // NB2*CAPB ints (9.4 MB)
    float*   gxp    = (float*)(bdata + (size_t)NB2 * CAPB);  // KCHUNKS*2048*128 f32 (16 MB)
    float*   hseq   = gxp + (size_t)KCHUNKS * ROWD * 128;    // 64 KB
    __half2* WihH   = (__half2*)(hseq + BATCH * WOUT * LSTMH); // 0.5 MB

    k_hist<<<NBLK, 256, 0, stream>>>(ei, hist2d);
    k_scan2<<<NB2, NBLK, 0, stream>>>(hist2d, bcnt);
    k_place<<<NBLK, 256, 0, stream>>>(ei, hist2d, bdata);
    k_csrsort<<<NB2, 512, 0, stream>>>(bcnt, bdata, rows, off, dinv, x, xsH);
    k_wihcvt<<<128 * ROWD / 4 / 256, 256, 0, stream>>>(Wih, WihH);

    k_agg1mlp<<<NN / 256, 256, 0, stream>>>(rows, off, dinv, xsH, W1, b1, W2, aggH);  // t2s
    k_aggcsr2<<<NN * 8 / 256, 256, 0, stream>>>(rows, off, dinv, aggH, b2, xsH);      // h2

    dim3 gg(ROWD / 32, KCHUNKS);
    k_gemmA<<<gg, 256, 0, stream>>>((const __half*)xsH, (const __half*)WihH, gxp);
    k_lstm<<<BATCH, 128, 0, stream>>>(gxp, Whh, bih, bhh, hseq);
    k_fc<<<2, 256, 0, stream>>>(hseq, Wfc1, bfc1, Wfc2, bfc2, out);
}

// Round 25
// 234.229 us; speedup vs baseline: 1.0558x; 1.0558x over previous
//
#include <hip/hip_runtime.h>
#include <hip/hip_fp16.h>

#define NN      262144    // N = B*WIN_IN*NODES
#define EDGES   2097152
#define FEATD   16
#define HIDD    64
#define LSTMH   32
#define BATCH   64
#define WIN     32
#define WOUT    8
#define NCLS    10
#define ROWD    2048      // NODES*FEAT = B*WIN (both 2048)
#define KCHUNKS 16
#define KSPAN   (ROWD / KCHUNKS)   // 128

#define NB2     512       // dest buckets: c >> 9 (512 nodes each)
#define NW      512       // nodes per bucket
#define CAPB    4608      // per-bucket capacity: Poisson(4096)+8 sigma
#define NBLK    256       // edge chunks
#define CHUNK   (EDGES / NBLK)   // 8192 edges per chunk

typedef __fp16 half4v __attribute__((ext_vector_type(4)));
typedef float  float4v __attribute__((ext_vector_type(4)));

// ---- phase 1: per-(block,bucket) histogram ----
__global__ void k_hist(const int* __restrict__ ei, int* __restrict__ hist2d) {
    __shared__ int h[NB2];
    int blk = blockIdx.x, tid = threadIdx.x;
    for (int l = tid; l < NB2; l += 256) h[l] = 0;
    __syncthreads();
    int e0 = blk * CHUNK;
    for (int i = tid; i < CHUNK; i += 256)
        atomicAdd(&h[ei[EDGES + e0 + i] >> 9], 1);
    __syncthreads();
    for (int l = tid; l < NB2; l += 256) hist2d[l * NBLK + blk] = h[l];
}

// ---- phase 2: per-bucket exclusive scan over block counts; totals -> bcnt ----
__global__ void k_scan2(int* __restrict__ hist2d, int* __restrict__ bcnt) {
    __shared__ int s[NBLK];
    int b = blockIdx.x, tid = threadIdx.x;
    int v = hist2d[b * NBLK + tid];
    s[tid] = v;
    __syncthreads();
    for (int off = 1; off < NBLK; off <<= 1) {
        int t = (tid >= off) ? s[tid - off] : 0;
        __syncthreads();
        s[tid] += t;
        __syncthreads();
    }
    hist2d[b * NBLK + tid] = s[tid] - v;   // exclusive base for (bucket, block)
    if (tid == NBLK - 1) bcnt[b] = s[tid];
}

// ---- phase 3: place edges into block-private contiguous runs (full lines) ----
__global__ void k_place(const int* __restrict__ ei, const int* __restrict__ hist2d,
                        int* __restrict__ bdata) {
    __shared__ int curp[NB2];
    int blk = blockIdx.x, tid = threadIdx.x;
    for (int l = tid; l < NB2; l += 256) curp[l] = hist2d[l * NBLK + blk];
    __syncthreads();
    int e0 = blk * CHUNK;
    for (int i = tid; i < CHUNK; i += 256) {
        int r = ei[e0 + i];
        int c = ei[EDGES + e0 + i];
        int b = c >> 9;
        int p = atomicAdd(&curp[b], 1);
        if (p < CAPB) bdata[(size_t)b * CAPB + p] = (r << 9) | (c & 511);
    }
}

// ---- per-bucket LDS counting sort (512 threads) + fused dinv + x pre-scale ----
__global__ void __launch_bounds__(512)
k_csrsort(const int* __restrict__ bcnt, const int* __restrict__ bdata,
          int* __restrict__ rows, int* __restrict__ offp, float* __restrict__ dinv,
          const float* __restrict__ x, __half2* __restrict__ xsH) {
    __shared__ int sidx[CAPB];          // 18.4 KB
    __shared__ int sorted[CAPB];        // 18.4 KB
    __shared__ int hist[NW], curp[NW], ssc[NW];
    __shared__ float sdinv[NW];
    int b = blockIdx.x, tid = threadIdx.x;
    int total = bcnt[b]; if (total > CAPB) total = CAPB;
    hist[tid] = 0;
    __syncthreads();
    const int* base = bdata + (size_t)b * CAPB;
    for (int i = tid; i < total; i += 512) {
        int w = base[i];
        sidx[i] = w;
        atomicAdd(&hist[w & 511], 1);
    }
    __syncthreads();
    int v = hist[tid];
    ssc[tid] = v;
    __syncthreads();
    for (int st = 1; st < NW; st <<= 1) {
        int t = (tid >= st) ? ssc[tid - st] : 0;
        __syncthreads();
        ssc[tid] += t;
        __syncthreads();
    }
    float dval = rsqrtf((float)v + 1.0f);
    curp[tid] = ssc[tid] - v;                       // exclusive start
    offp[b * NW + tid] = ssc[tid];                  // inclusive end
    dinv[b * NW + tid] = dval;                      // degree byproduct
    sdinv[tid] = dval;
    __syncthreads();
    for (int i = tid; i < total; i += 512) {
        int w = sidx[i];
        int pos = atomicAdd(&curp[w & 511], 1);
        sorted[pos] = w >> 9;
    }
    // fused pre-scale for this bucket's 512 nodes
    for (int i = tid; i < NW * 8; i += 512) {
        int nl = i >> 3;
        float d = sdinv[nl];
        float2 xv = ((const float2*)x)[(size_t)(b * NW) * 8 + i];
        xsH[(size_t)(b * NW) * 8 + i] = __floats2half2_rn(xv.x * d, xv.y * d);
    }
    __syncthreads();
    for (int i = tid; i < total; i += 512) rows[(size_t)b * CAPB + i] = sorted[i];
}

// ---- Wih f32 -> f16 ----
__global__ void k_wihcvt(const float* __restrict__ Wih, __half2* __restrict__ WihH) {
    int i = blockIdx.x * blockDim.x + threadIdx.x;   // 65536 float4 lanes
    if (i >= 128 * ROWD / 4) return;
    float4 v = ((const float4*)Wih)[i];
    WihH[i * 2 + 0] = __floats2half2_rn(v.x, v.y);
    WihH[i * 2 + 1] = __floats2half2_rn(v.z, v.w);
}

// ---- zero-atomic CSR gather-reduce, f32 accumulate, fused self (+b2,relu L2) ----
template<int LAYER>
__global__ void __launch_bounds__(256)
k_aggcsr(const int* __restrict__ rows, const int* __restrict__ off,
         const float* __restrict__ dinv, const __half2* __restrict__ srcH,
         const float* __restrict__ b2, __half2* __restrict__ outH) {
    int i = blockIdx.x * blockDim.x + threadIdx.x;
    if (i >= NN * 8) return;
    int n = i >> 3, f2 = i & 7;
    int begin = (n & 511) ? off[n - 1] : 0;
    int end = off[n];
    const size_t base = (size_t)(n >> 9) * CAPB;
    float2 selfv = __half22float2(srcH[(size_t)n * 8 + f2]);
    float ax = selfv.x, ay = selfv.y;
    for (size_t e = base + begin; e < base + end; ++e) {
        int r = rows[e];
        float2 v = __half22float2(srcH[(size_t)r * 8 + f2]);
        ax += v.x; ay += v.y;
    }
    float d = dinv[n];
    ax *= d; ay *= d;
    if (LAYER == 2) {
        ax = fmaxf(ax + b2[f2 * 2 + 0], 0.f);
        ay = fmaxf(ay + b2[f2 * 2 + 1], 0.f);
    }
    outH[i] = __floats2half2_rn(ax, ay);
}

// ---- fused MLP: hid = relu(in1@W1+b1) ; t2s = (hid@W2)*dinv -> fp16 over xsH ----
__global__ void k_gcnmlp(const __half2* __restrict__ in1H, __half2* __restrict__ xsH,
                         const float* __restrict__ dinv,
                         const float* __restrict__ W1, const float* __restrict__ b1,
                         const float* __restrict__ W2) {
    __shared__ float sW1[FEATD * HIDD];
    __shared__ float sW2[HIDD * FEATD];
    __shared__ float sb1[HIDD];
    for (int l = threadIdx.x; l < FEATD * HIDD; l += blockDim.x) {
        sW1[l] = W1[l];
        sW2[l] = W2[l];
    }
    if (threadIdx.x < HIDD) sb1[threadIdx.x] = b1[threadIdx.x];
    __syncthreads();
    int n = blockIdx.x * blockDim.x + threadIdx.x;
    if (n >= NN) return;
    union { float4 f4; __half2 h2[4]; } a0, a1;
    a0.f4 = ((const float4*)(in1H + (size_t)n * 8))[0];
    a1.f4 = ((const float4*)(in1H + (size_t)n * 8))[1];
    float in[FEATD];
#pragma unroll
    for (int q = 0; q < 4; q++) {
        float2 v = __half22float2(a0.h2[q]);
        in[q * 2 + 0] = v.x; in[q * 2 + 1] = v.y;
        v = __half22float2(a1.h2[q]);
        in[8 + q * 2 + 0] = v.x; in[8 + q * 2 + 1] = v.y;
    }
    float out[FEATD];
#pragma unroll
    for (int c = 0; c < FEATD; c++) out[c] = 0.f;
#pragma unroll 8
    for (int j = 0; j < HIDD; j++) {
        float h = sb1[j];
#pragma unroll
        for (int f = 0; f < FEATD; f++) h += in[f] * sW1[f * HIDD + j];
        h = fmaxf(h, 0.f);
#pragma unroll
        for (int c = 0; c < FEATD; c++) out[c] += h * sW2[j * FEATD + c];
    }
    float dn = dinv[n];
    union { float4 f4; __half2 h2[4]; } o0, o1;
#pragma unroll
    for (int q = 0; q < 4; q++) {
        o0.h2[q] = __floats2half2_rn(out[q * 2] * dn, out[q * 2 + 1] * dn);
        o1.h2[q] = __floats2half2_rn(out[8 + q * 2] * dn, out[8 + q * 2 + 1] * dn);
    }
    ((float4*)(xsH + (size_t)n * 8))[0] = o0.f4;
    ((float4*)(xsH + (size_t)n * 8))[1] = o1.f4;
}

// ---- LSTM input GEMM via MFMA 16x16x16 f16 ----
__global__ void __launch_bounds__(256)
k_gemmA(const __half* __restrict__ h2, const __half* __restrict__ WihH,
        float* __restrict__ gxp) {
    __shared__ __half Bs[128][KSPAN + 8];   // 34.8 KB
    int tid = threadIdx.x;
    int row0 = blockIdx.x * 32;
    int k0 = blockIdx.y * KSPAN;
    for (int idx = tid; idx < 128 * (KSPAN / 8); idx += 256) {
        int j = idx >> 4, c8 = (idx & 15) * 8;
        *(float4*)&Bs[j][c8] = *(const float4*)&WihH[(size_t)j * ROWD + k0 + c8];
    }
    __syncthreads();
    int w = tid >> 6;
    int l = tid & 63;
    int rt = w & 1;            // row tile (16 rows)
    int ch = w >> 1;           // col half (64 cols)
    int m = l & 15;
    int kg = l >> 4;
    float4v acc0 = {0.f, 0.f, 0.f, 0.f};
    float4v acc1 = {0.f, 0.f, 0.f, 0.f};
    float4v acc2 = {0.f, 0.f, 0.f, 0.f};
    float4v acc3 = {0.f, 0.f, 0.f, 0.f};
    const __half* aptr = h2 + (size_t)(row0 + rt * 16 + m) * ROWD + k0 + kg * 4;
#pragma unroll
    for (int kk = 0; kk < KSPAN; kk += 16) {
        half4v a = *(const half4v*)(aptr + kk);
        half4v b0 = *(const half4v*)&Bs[ch * 64 + 0 * 16 + m][kk + kg * 4];
        half4v b1 = *(const half4v*)&Bs[ch * 64 + 1 * 16 + m][kk + kg * 4];
        half4v b2 = *(const half4v*)&Bs[ch * 64 + 2 * 16 + m][kk + kg * 4];
        half4v b3 = *(const half4v*)&Bs[ch * 64 + 3 * 16 + m][kk + kg * 4];
        acc0 = __builtin_amdgcn_mfma_f32_16x16x16f16(a, b0, acc0, 0, 0, 0);
        acc1 = __builtin_amdgcn_mfma_f32_16x16x16f16(a, b1, acc1, 0, 0, 0);
        acc2 = __builtin_amdgcn_mfma_f32_16x16x16f16(a, b2, acc2, 0, 0, 0);
        acc3 = __builtin_amdgcn_mfma_f32_16x16x16f16(a, b3, acc3, 0, 0, 0);
    }
    float* ob = gxp + (size_t)blockIdx.y * (ROWD * 128) + (size_t)(row0 + rt * 16) * 128 + ch * 64;
#pragma unroll
    for (int i = 0; i < 4; i++) {
        size_t ro = (size_t)(kg * 4 + i) * 128;
        ob[ro + 0 * 16 + m] = acc0[i];
        ob[ro + 1 * 16 + m] = acc1[i];
        ob[ro + 2 * 16 + m] = acc2[i];
        ob[ro + 3 * 16 + m] = acc3[i];
    }
}

// ---- LSTM recurrence with fused gxp prereduce ----
__global__ void k_lstm(const float* __restrict__ gxp, const float* __restrict__ Whh,
                       const float* __restrict__ bih, const float* __restrict__ bhh,
                       float* __restrict__ hseq) {
    __shared__ float sWhhT[LSTMH][4 * LSTMH];   // [k][j] = Whh[j][k]
    __shared__ float sgxL[WIN * 4 * LSTMH];      // 16 KB
    __shared__ float sh[LSTMH], sc[LSTMH], sg[4 * LSTMH];
    int b = blockIdx.x, j = threadIdx.x;
    for (int l = j; l < 4 * LSTMH * LSTMH; l += 4 * LSTMH) {
        int r = l >> 5, k = l & 31;
        sWhhT[k][r] = Whh[l];
    }
    for (int l = j; l < WIN * 128; l += 128) {
        float s = 0.f;
#pragma unroll
        for (int p = 0; p < KCHUNKS; p++)
            s += gxp[(size_t)p * ROWD * 128 + (size_t)b * WIN * 128 + l];
        sgxL[l] = s;
    }
    float bias = bih[j] + bhh[j];
    if (j < LSTMH) { sh[j] = 0.f; sc[j] = 0.f; }
    __syncthreads();
    for (int t = 0; t < WIN; t++) {
        float g = bias + sgxL[t * 128 + j];
#pragma unroll
        for (int k = 0; k < LSTMH; k++) g += sWhhT[k][j] * sh[k];
        sg[j] = g;
        __syncthreads();
        if (j < LSTMH) {
            float ig = sg[j], fg = sg[32 + j], gg = sg[64 + j], og = sg[96 + j];
            float c = sc[j];
            float si = 1.f / (1.f + __expf(-ig));
            float sf = 1.f / (1.f + __expf(-fg));
            float so = 1.f / (1.f + __expf(-og));
            c = sf * c + si * tanhf(gg);
            float h = so * tanhf(c);
            sc[j] = c; sh[j] = h;
            if (t >= WIN - WOUT)
                hseq[(size_t)(b * WOUT + (t - (WIN - WOUT))) * LSTMH + j] = h;
        }
        __syncthreads();
    }
}

// ---- FC head: (512 rows) 32 -> 16 relu -> 10 ----
__global__ void k_fc(const float* __restrict__ hseq, const float* __restrict__ Wfc1,
                     const float* __restrict__ bfc1, const float* __restrict__ Wfc2,
                     const float* __restrict__ bfc2, float* __restrict__ out) {
    __shared__ float sW1[16 * 32], sb1[16], sW2[10 * 16], sb2[10];
    int tid = threadIdx.x;
    for (int l = tid; l < 16 * 32; l += blockDim.x) sW1[l] = Wfc1[l];
    if (tid < 16) sb1[tid] = bfc1[tid];
    for (int l = tid; l < 160; l += blockDim.x) sW2[l] = Wfc2[l];
    if (tid < 10) sb2[tid] = bfc2[tid];
    __syncthreads();
    int r = blockIdx.x * blockDim.x + tid;
    if (r >= BATCH * WOUT) return;
    float h[32];
#pragma unroll
    for (int k = 0; k < 32; k++) h[k] = hseq[(size_t)r * 32 + k];
    float hid[16];
#pragma unroll
    for (int j = 0; j < 16; j++) {
        float v = sb1[j];
#pragma unroll
        for (int k = 0; k < 32; k++) v += sW1[j * 32 + k] * h[k];
        hid[j] = fmaxf(v, 0.f);
    }
#pragma unroll
    for (int c = 0; c < NCLS; c++) {
        float v = sb2[c];
#pragma unroll
        for (int j = 0; j < 16; j++) v += sW2[c * 16 + j] * hid[j];
        out[(size_t)r * NCLS + c] = v;
    }
}

extern "C" void kernel_launch(void* const* d_in, const int* in_sizes, int n_in,
                              void* d_out, int out_size, void* d_ws, size_t ws_size,
                              hipStream_t stream) {
    const float* x    = (const float*)d_in[0];
    const int*   ei   = (const int*)d_in[1];
    const float* W1   = (const float*)d_in[2];
    const float* b1   = (const float*)d_in[3];
    const float* W2   = (const float*)d_in[4];
    const float* b2   = (const float*)d_in[5];
    const float* Wih  = (const float*)d_in[6];
    const float* Whh  = (const float*)d_in[7];
    const float* bih  = (const float*)d_in[8];
    const float* bhh  = (const float*)d_in[9];
    const float* Wfc1 = (const float*)d_in[10];
    const float* bfc1 = (const float*)d_in[11];
    const float* Wfc2 = (const float*)d_in[12];
    const float* bfc2 = (const float*)d_in[13];
    float* out = (float*)d_out;

    float*   ws     = (float*)d_ws;
    float*   dinv   = ws;                                    // NN f32 (1 MB)
    int*     hist2d = (int*)(dinv + NN);                     // NB2*NBLK ints (0.5 MB)
    int*     bcnt   = hist2d + NB2 * NBLK;                   // NB2 ints
    int*     off    = bcnt + NB2;                            // NN ints (1 MB)
    int*     rows   = off + NN;                              // NB2*CAPB ints (9.4 MB)
    __half2* aggH   = (__half2*)(rows + (size_t)NB2 * CAPB); // NN*8 half2 (8 MB): in1/h2
    __half2* xsH    = aggH + (size_t)NN * 8;                 // NN*8 half2 (8 MB): xs -> t2s
    int*     bdata  = (int*)(xsH + (size_t)NN * 8);          // NB2*CAPB ints (9.4 MB)
    float*   gxp    = (float*)(bdata + (size_t)NB2 * CAPB);  // KCHUNKS*2048*128 f32 (16 MB)
    float*   hseq   = gxp + (size_t)KCHUNKS * ROWD * 128;    // 64 KB
    __half2* WihH   = (__half2*)(hseq + BATCH * WOUT * LSTMH); // 0.5 MB

    k_hist<<<NBLK, 256, 0, stream>>>(ei, hist2d);
    k_scan2<<<NB2, NBLK, 0, stream>>>(hist2d, bcnt);
    k_place<<<NBLK, 256, 0, stream>>>(ei, hist2d, bdata);
    k_csrsort<<<NB2, 512, 0, stream>>>(bcnt, bdata, rows, off, dinv, x, xsH);
    k_wihcvt<<<128 * ROWD / 4 / 256, 256, 0, stream>>>(Wih, WihH);

    k_aggcsr<1><<<NN * 8 / 256, 256, 0, stream>>>(rows, off, dinv, xsH, b2, aggH);  // in1
    k_gcnmlp<<<NN / 256, 256, 0, stream>>>(aggH, xsH, dinv, W1, b1, W2);            // t2s
    k_aggcsr<2><<<NN * 8 / 256, 256, 0, stream>>>(rows, off, dinv, xsH, b2, aggH);  // h2

    dim3 gg(ROWD / 32, KCHUNKS);
    k_gemmA<<<gg, 256, 0, stream>>>((const __half*)aggH, (const __half*)WihH, gxp);
    k_lstm<<<BATCH, 128, 0, stream>>>(gxp, Whh, bih, bhh, hseq);
    k_fc<<<2, 256, 0, stream>>>(hseq, Wfc1, bfc1, Wfc2, bfc2, out);
}

// Round 26
// 222.188 us; speedup vs baseline: 1.1131x; 1.0542x over previous
//
#include <hip/hip_runtime.h>
#include <hip/hip_fp16.h>

#define NN      262144    // N = B*WIN_IN*NODES
#define EDGES   2097152
#define FEATD   16
#define HIDD    64
#define LSTMH   32
#define BATCH   64
#define WIN     32
#define WOUT    8
#define NCLS    10
#define ROWD    2048      // NODES*FEAT = B*WIN (both 2048)
#define KCHUNKS 16
#define KSPAN   (ROWD / KCHUNKS)   // 128

#define NB2     512       // dest buckets: c >> 9 (512 nodes each)
#define NW      512       // nodes per bucket
#define CAPB    4608      // per-bucket capacity: Poisson(4096)+8 sigma
#define NBLK    256       // edge chunks
#define CHUNK   (EDGES / NBLK)   // 8192 edges per chunk

typedef __fp16 half4v __attribute__((ext_vector_type(4)));
typedef float  float4v __attribute__((ext_vector_type(4)));

// ---- phase 1: per-(block,bucket) histogram ----
__global__ void k_hist(const int* __restrict__ ei, int* __restrict__ hist2d) {
    __shared__ int h[NB2];
    int blk = blockIdx.x, tid = threadIdx.x;
    for (int l = tid; l < NB2; l += 256) h[l] = 0;
    __syncthreads();
    int e0 = blk * CHUNK;
    for (int i = tid; i < CHUNK; i += 256)
        atomicAdd(&h[ei[EDGES + e0 + i] >> 9], 1);
    __syncthreads();
    for (int l = tid; l < NB2; l += 256) hist2d[l * NBLK + blk] = h[l];
}

// ---- phase 2: per-bucket exclusive scan over block counts; totals -> bcnt ----
__global__ void k_scan2(int* __restrict__ hist2d, int* __restrict__ bcnt) {
    __shared__ int s[NBLK];
    int b = blockIdx.x, tid = threadIdx.x;
    int v = hist2d[b * NBLK + tid];
    s[tid] = v;
    __syncthreads();
    for (int off = 1; off < NBLK; off <<= 1) {
        int t = (tid >= off) ? s[tid - off] : 0;
        __syncthreads();
        s[tid] += t;
        __syncthreads();
    }
    hist2d[b * NBLK + tid] = s[tid] - v;   // exclusive base for (bucket, block)
    if (tid == NBLK - 1) bcnt[b] = s[tid];
}

// ---- phase 3: place edges into block-private contiguous runs (full lines) ----
__global__ void k_place(const int* __restrict__ ei, const int* __restrict__ hist2d,
                        int* __restrict__ bdata) {
    __shared__ int curp[NB2];
    int blk = blockIdx.x, tid = threadIdx.x;
    for (int l = tid; l < NB2; l += 256) curp[l] = hist2d[l * NBLK + blk];
    __syncthreads();
    int e0 = blk * CHUNK;
    for (int i = tid; i < CHUNK; i += 256) {
        int r = ei[e0 + i];
        int c = ei[EDGES + e0 + i];
        int b = c >> 9;
        int p = atomicAdd(&curp[b], 1);
        if (p < CAPB) bdata[(size_t)b * CAPB + p] = (r << 9) | (c & 511);
    }
}

// ---- per-bucket LDS counting sort (512 threads) + fused dinv + x pre-scale ----
__global__ void __launch_bounds__(512)
k_csrsort(const int* __restrict__ bcnt, const int* __restrict__ bdata,
          int* __restrict__ rows, int* __restrict__ offp, float* __restrict__ dinv,
          const float* __restrict__ x, __half2* __restrict__ xsH) {
    __shared__ int sidx[CAPB];          // 18.4 KB
    __shared__ int sorted[CAPB];        // 18.4 KB
    __shared__ int hist[NW], curp[NW], ssc[NW];
    __shared__ float sdinv[NW];
    int b = blockIdx.x, tid = threadIdx.x;
    int total = bcnt[b]; if (total > CAPB) total = CAPB;
    hist[tid] = 0;
    __syncthreads();
    const int* base = bdata + (size_t)b * CAPB;
    for (int i = tid; i < total; i += 512) {
        int w = base[i];
        sidx[i] = w;
        atomicAdd(&hist[w & 511], 1);
    }
    __syncthreads();
    int v = hist[tid];
    ssc[tid] = v;
    __syncthreads();
    for (int st = 1; st < NW; st <<= 1) {
        int t = (tid >= st) ? ssc[tid - st] : 0;
        __syncthreads();
        ssc[tid] += t;
        __syncthreads();
    }
    float dval = rsqrtf((float)v + 1.0f);
    curp[tid] = ssc[tid] - v;                       // exclusive start
    offp[b * NW + tid] = ssc[tid];                  // inclusive end
    dinv[b * NW + tid] = dval;                      // degree byproduct
    sdinv[tid] = dval;
    __syncthreads();
    for (int i = tid; i < total; i += 512) {
        int w = sidx[i];
        int pos = atomicAdd(&curp[w & 511], 1);
        sorted[pos] = w >> 9;
    }
    // fused pre-scale for this bucket's 512 nodes
    for (int i = tid; i < NW * 8; i += 512) {
        int nl = i >> 3;
        float d = sdinv[nl];
        float2 xv = ((const float2*)x)[(size_t)(b * NW) * 8 + i];
        xsH[(size_t)(b * NW) * 8 + i] = __floats2half2_rn(xv.x * d, xv.y * d);
    }
    __syncthreads();
    for (int i = tid; i < total; i += 512) rows[(size_t)b * CAPB + i] = sorted[i];
}

// ---- Wih f32 -> f16 ----
__global__ void k_wihcvt(const float* __restrict__ Wih, __half2* __restrict__ WihH) {
    int i = blockIdx.x * blockDim.x + threadIdx.x;   // 65536 float4 lanes
    if (i >= 128 * ROWD / 4) return;
    float4 v = ((const float4*)Wih)[i];
    WihH[i * 2 + 0] = __floats2half2_rn(v.x, v.y);
    WihH[i * 2 + 1] = __floats2half2_rn(v.z, v.w);
}

// ---- zero-atomic CSR gather-reduce, f32 accumulate, fused self (+b2,relu L2) ----
template<int LAYER>
__global__ void __launch_bounds__(256)
k_aggcsr(const int* __restrict__ rows, const int* __restrict__ off,
         const float* __restrict__ dinv, const __half2* __restrict__ srcH,
         const float* __restrict__ b2, __half2* __restrict__ outH) {
    int i = blockIdx.x * blockDim.x + threadIdx.x;
    if (i >= NN * 8) return;
    int n = i >> 3, f2 = i & 7;
    int begin = (n & 511) ? off[n - 1] : 0;
    int end = off[n];
    const size_t base = (size_t)(n >> 9) * CAPB;
    float2 selfv = __half22float2(srcH[(size_t)n * 8 + f2]);
    float ax = selfv.x, ay = selfv.y;
    for (size_t e = base + begin; e < base + end; ++e) {
        int r = rows[e];
        float2 v = __half22float2(srcH[(size_t)r * 8 + f2]);
        ax += v.x; ay += v.y;
    }
    float d = dinv[n];
    ax *= d; ay *= d;
    if (LAYER == 2) {
        ax = fmaxf(ax + b2[f2 * 2 + 0], 0.f);
        ay = fmaxf(ay + b2[f2 * 2 + 1], 0.f);
    }
    outH[i] = __floats2half2_rn(ax, ay);
}

// ---- fused MLP: hid = relu(in1@W1+b1) ; t2s = (hid@W2)*dinv -> fp16 over xsH ----
__global__ void k_gcnmlp(const __half2* __restrict__ in1H, __half2* __restrict__ xsH,
                         const float* __restrict__ dinv,
                         const float* __restrict__ W1, const float* __restrict__ b1,
                         const float* __restrict__ W2) {
    __shared__ float sW1[FEATD * HIDD];
    __shared__ float sW2[HIDD * FEATD];
    __shared__ float sb1[HIDD];
    for (int l = threadIdx.x; l < FEATD * HIDD; l += blockDim.x) {
        sW1[l] = W1[l];
        sW2[l] = W2[l];
    }
    if (threadIdx.x < HIDD) sb1[threadIdx.x] = b1[threadIdx.x];
    __syncthreads();
    int n = blockIdx.x * blockDim.x + threadIdx.x;
    if (n >= NN) return;
    union { float4 f4; __half2 h2[4]; } a0, a1;
    a0.f4 = ((const float4*)(in1H + (size_t)n * 8))[0];
    a1.f4 = ((const float4*)(in1H + (size_t)n * 8))[1];
    float in[FEATD];
#pragma unroll
    for (int q = 0; q < 4; q++) {
        float2 v = __half22float2(a0.h2[q]);
        in[q * 2 + 0] = v.x; in[q * 2 + 1] = v.y;
        v = __half22float2(a1.h2[q]);
        in[8 + q * 2 + 0] = v.x; in[8 + q * 2 + 1] = v.y;
    }
    float out[FEATD];
#pragma unroll
    for (int c = 0; c < FEATD; c++) out[c] = 0.f;
#pragma unroll 8
    for (int j = 0; j < HIDD; j++) {
        float h = sb1[j];
#pragma unroll
        for (int f = 0; f < FEATD; f++) h += in[f] * sW1[f * HIDD + j];
        h = fmaxf(h, 0.f);
#pragma unroll
        for (int c = 0; c < FEATD; c++) out[c] += h * sW2[j * FEATD + c];
    }
    float dn = dinv[n];
    union { float4 f4; __half2 h2[4]; } o0, o1;
#pragma unroll
    for (int q = 0; q < 4; q++) {
        o0.h2[q] = __floats2half2_rn(out[q * 2] * dn, out[q * 2 + 1] * dn);
        o1.h2[q] = __floats2half2_rn(out[8 + q * 2] * dn, out[8 + q * 2 + 1] * dn);
    }
    ((float4*)(xsH + (size_t)n * 8))[0] = o0.f4;
    ((float4*)(xsH + (size_t)n * 8))[1] = o1.f4;
}

// ---- LSTM input GEMM via MFMA 16x16x16 f16 ----
__global__ void __launch_bounds__(256)
k_gemmA(const __half* __restrict__ h2, const __half* __restrict__ WihH,
        float* __restrict__ gxp) {
    __shared__ __half Bs[128][KSPAN + 8];   // 34.8 KB
    int tid = threadIdx.x;
    int row0 = blockIdx.x * 32;
    int k0 = blockIdx.y * KSPAN;
    for (int idx = tid; idx < 128 * (KSPAN / 8); idx += 256) {
        int j = idx >> 4, c8 = (idx & 15) * 8;
        *(float4*)&Bs[j][c8] = *(const float4*)&WihH[(size_t)j * ROWD + k0 + c8];
    }
    __syncthreads();
    int w = tid >> 6;
    int l = tid & 63;
    int rt = w & 1;            // row tile (16 rows)
    int ch = w >> 1;           // col half (64 cols)
    int m = l & 15;
    int kg = l >> 4;
    float4v acc0 = {0.f, 0.f, 0.f, 0.f};
    float4v acc1 = {0.f, 0.f, 0.f, 0.f};
    float4v acc2 = {0.f, 0.f, 0.f, 0.f};
    float4v acc3 = {0.f, 0.f, 0.f, 0.f};
    const __half* aptr = h2 + (size_t)(row0 + rt * 16 + m) * ROWD + k0 + kg * 4;
#pragma unroll
    for (int kk = 0; kk < KSPAN; kk += 16) {
        half4v a = *(const half4v*)(aptr + kk);
        half4v b0 = *(const half4v*)&Bs[ch * 64 + 0 * 16 + m][kk + kg * 4];
        half4v b1 = *(const half4v*)&Bs[ch * 64 + 1 * 16 + m][kk + kg * 4];
        half4v b2 = *(const half4v*)&Bs[ch * 64 + 2 * 16 + m][kk + kg * 4];
        half4v b3 = *(const half4v*)&Bs[ch * 64 + 3 * 16 + m][kk + kg * 4];
        acc0 = __builtin_amdgcn_mfma_f32_16x16x16f16(a, b0, acc0, 0, 0, 0);
        acc1 = __builtin_amdgcn_mfma_f32_16x16x16f16(a, b1, acc1, 0, 0, 0);
        acc2 = __builtin_amdgcn_mfma_f32_16x16x16f16(a, b2, acc2, 0, 0, 0);
        acc3 = __builtin_amdgcn_mfma_f32_16x16x16f16(a, b3, acc3, 0, 0, 0);
    }
    float* ob = gxp + (size_t)blockIdx.y * (ROWD * 128) + (size_t)(row0 + rt * 16) * 128 + ch * 64;
#pragma unroll
    for (int i = 0; i < 4; i++) {
        size_t ro = (size_t)(kg * 4 + i) * 128;
        ob[ro + 0 * 16 + m] = acc0[i];
        ob[ro + 1 * 16 + m] = acc1[i];
        ob[ro + 2 * 16 + m] = acc2[i];
        ob[ro + 3 * 16 + m] = acc3[i];
    }
}

// ---- gxp partial-sum prereduce (1024 blocks, full-device parallel) ----
__global__ void k_pre(const float* __restrict__ gxp, float* __restrict__ sgx) {
    int i = blockIdx.x * blockDim.x + threadIdx.x;   // ROWD*128 lanes
    if (i >= ROWD * 128) return;
    float s = 0.f;
#pragma unroll
    for (int p = 0; p < KCHUNKS; p++) s += gxp[(size_t)p * ROWD * 128 + i];
    sgx[i] = s;
}

// ---- LSTM recurrence (reads pre-summed sgx) ----
__global__ void k_lstm(const float* __restrict__ sgx, const float* __restrict__ Whh,
                       const float* __restrict__ bih, const float* __restrict__ bhh,
                       float* __restrict__ hseq) {
    __shared__ float sWhhT[LSTMH][4 * LSTMH];   // [k][j] = Whh[j][k]
    __shared__ float sgxL[WIN * 4 * LSTMH];      // 16 KB
    __shared__ float sh[LSTMH], sc[LSTMH], sg[4 * LSTMH];
    int b = blockIdx.x, j = threadIdx.x;
    for (int l = j; l < 4 * LSTMH * LSTMH; l += 4 * LSTMH) {
        int r = l >> 5, k = l & 31;
        sWhhT[k][r] = Whh[l];
    }
    for (int l = j; l < WIN * 128; l += 128) sgxL[l] = sgx[(size_t)b * WIN * 128 + l];
    float bias = bih[j] + bhh[j];
    if (j < LSTMH) { sh[j] = 0.f; sc[j] = 0.f; }
    __syncthreads();
    for (int t = 0; t < WIN; t++) {
        float g = bias + sgxL[t * 128 + j];
#pragma unroll
        for (int k = 0; k < LSTMH; k++) g += sWhhT[k][j] * sh[k];
        sg[j] = g;
        __syncthreads();
        if (j < LSTMH) {
            float ig = sg[j], fg = sg[32 + j], gg = sg[64 + j], og = sg[96 + j];
            float c = sc[j];
            float si = 1.f / (1.f + __expf(-ig));
            float sf = 1.f / (1.f + __expf(-fg));
            float so = 1.f / (1.f + __expf(-og));
            c = sf * c + si * tanhf(gg);
            float h = so * tanhf(c);
            sc[j] = c; sh[j] = h;
            if (t >= WIN - WOUT)
                hseq[(size_t)(b * WOUT + (t - (WIN - WOUT))) * LSTMH + j] = h;
        }
        __syncthreads();
    }
}

// ---- FC head: (512 rows) 32 -> 16 relu -> 10 ----
__global__ void k_fc(const float* __restrict__ hseq, const float* __restrict__ Wfc1,
                     const float* __restrict__ bfc1, const float* __restrict__ Wfc2,
                     const float* __restrict__ bfc2, float* __restrict__ out) {
    __shared__ float sW1[16 * 32], sb1[16], sW2[10 * 16], sb2[10];
    int tid = threadIdx.x;
    for (int l = tid; l < 16 * 32; l += blockDim.x) sW1[l] = Wfc1[l];
    if (tid < 16) sb1[tid] = bfc1[tid];
    for (int l = tid; l < 160; l += blockDim.x) sW2[l] = Wfc2[l];
    if (tid < 10) sb2[tid] = bfc2[tid];
    __syncthreads();
    int r = blockIdx.x * blockDim.x + tid;
    if (r >= BATCH * WOUT) return;
    float h[32];
#pragma unroll
    for (int k = 0; k < 32; k++) h[k] = hseq[(size_t)r * 32 + k];
    float hid[16];
#pragma unroll
    for (int j = 0; j < 16; j++) {
        float v = sb1[j];
#pragma unroll
        for (int k = 0; k < 32; k++) v += sW1[j * 32 + k] * h[k];
        hid[j] = fmaxf(v, 0.f);
    }
#pragma unroll
    for (int c = 0; c < NCLS; c++) {
        float v = sb2[c];
#pragma unroll
        for (int j = 0; j < 16; j++) v += sW2[c * 16 + j] * hid[j];
        out[(size_t)r * NCLS + c] = v;
    }
}

extern "C" void kernel_launch(void* const* d_in, const int* in_sizes, int n_in,
                              void* d_out, int out_size, void* d_ws, size_t ws_size,
                              hipStream_t stream) {
    const float* x    = (const float*)d_in[0];
    const int*   ei   = (const int*)d_in[1];
    const float* W1   = (const float*)d_in[2];
    const float* b1   = (const float*)d_in[3];
    const float* W2   = (const float*)d_in[4];
    const float* b2   = (const float*)d_in[5];
    const float* Wih  = (const float*)d_in[6];
    const float* Whh  = (const float*)d_in[7];
    const float* bih  = (const float*)d_in[8];
    const float* bhh  = (const float*)d_in[9];
    const float* Wfc1 = (const float*)d_in[10];
    const float* bfc1 = (const float*)d_in[11];
    const float* Wfc2 = (const float*)d_in[12];
    const float* bfc2 = (const float*)d_in[13];
    float* out = (float*)d_out;

    float*   ws     = (float*)d_ws;
    float*   dinv   = ws;                                    // NN f32 (1 MB)
    int*     hist2d = (int*)(dinv + NN);                     // NB2*NBLK ints (0.5 MB)
    int*     bcnt   = hist2d + NB2 * NBLK;                   // NB2 ints
    int*     off    = bcnt + NB2;                            // NN ints (1 MB)
    int*     rows   = off + NN;                              // NB2*CAPB ints (9.4 MB)
    __half2* aggH   = (__half2*)(rows + (size_t)NB2 * CAPB); // NN*8 half2 (8 MB): in1/h2
    __half2* xsH    = aggH + (size_t)NN * 8;                 // NN*8 half2 (8 MB): xs -> t2s
    int*     bdata  = (int*)(xsH + (size_t)NN * 8);          // NB2*CAPB ints (9.4 MB)
    float*   gxp    = (float*)(bdata + (size_t)NB2 * CAPB);  // KCHUNKS*2048*128 f32 (16 MB)
    float*   sgx    = gxp + (size_t)KCHUNKS * ROWD * 128;    // 1 MB
    float*   hseq   = sgx + ROWD * 128;                      // 64 KB
    __half2* WihH   = (__half2*)(hseq + BATCH * WOUT * LSTMH); // 0.5 MB

    k_hist<<<NBLK, 256, 0, stream>>>(ei, hist2d);
    k_scan2<<<NB2, NBLK, 0, stream>>>(hist2d, bcnt);
    k_place<<<NBLK, 256, 0, stream>>>(ei, hist2d, bdata);
    k_csrsort<<<NB2, 512, 0, stream>>>(bcnt, bdata, rows, off, dinv, x, xsH);
    k_wihcvt<<<128 * ROWD / 4 / 256, 256, 0, stream>>>(Wih, WihH);

    k_aggcsr<1><<<NN * 8 / 256, 256, 0, stream>>>(rows, off, dinv, xsH, b2, aggH);  // in1
    k_gcnmlp<<<NN / 256, 256, 0, stream>>>(aggH, xsH, dinv, W1, b1, W2);            // t2s
    k_aggcsr<2><<<NN * 8 / 256, 256, 0, stream>>>(rows, off, dinv, xsH, b2, aggH);  // h2

    dim3 gg(ROWD / 32, KCHUNKS);
    k_gemmA<<<gg, 256, 0, stream>>>((const __half*)aggH, (const __half*)WihH, gxp);
    k_pre<<<ROWD * 128 / 256, 256, 0, stream>>>(gxp, sgx);
    k_lstm<<<BATCH, 128, 0, stream>>>(sgx, Whh, bih, bhh, hseq);
    k_fc<<<2, 256, 0, stream>>>(hseq, Wfc1, bfc1, Wfc2, bfc2, out);
}